// Round 5
// baseline (111.326 us; speedup 1.0000x reference)
//
#include <hip/hip_runtime.h>
#include <math.h>

#define Hdim    256                    // embedding dim
#define NMAX    8192
#define NCLS    13
#define NPADMAX (NMAX + 6 * 32)        // only classes 1..6 bucketed, padded to 32
#define WLMAX   264                    // max 32-anchor wave-tiles (all-one-class worst case)
#define NSPLIT  16                     // j-range splits per wave-tile
#define WPB     4                      // waves per block in sim kernel
#define SIMGRID ((WLMAX * NSPLIT) / WPB)
#define BIGV    1e9f
#define MARGIN  0.5f

typedef __attribute__((ext_vector_type(8))) short bf16x8;   // MFMA A/B frag
typedef __attribute__((ext_vector_type(4))) float f32x4;    // MFMA C/D frag

struct WS {
    unsigned short ebf[NPADMAX][Hdim]; // bucket-sorted normalized bf16 rows (classes 1..6)
    unsigned hpK[NPADMAX];             // hardest-pos keys (min)
    unsigned hnK[NPADMAX];             // hardest-neg keys (max)
    int labG[NPADMAX];                 // gathered labels (-1 = pad)
    int gpos[NMAX];                    // original row -> gathered row (-1 = not bucketed)
    int S[8];                          // S[1..6] bucket starts, S[7] = padded end
    int n[8];                          // real bucket counts, classes 1..6
    int wl_a[WLMAX];                   // worklist: anchor base (gathered)
    int wl_c[WLMAX];                   // worklist: class
    int T;                             // worklist length
    unsigned done;                     // sim-block completion counter
};

__device__ inline unsigned short f2bf(float f) {
    unsigned u = __float_as_uint(f);
    return (unsigned short)((u + 0x7fffu + ((u >> 16) & 1u)) >> 16);
}
__device__ inline unsigned fkey(float f) {           // order-preserving float->uint
    unsigned u = __float_as_uint(f);
    return (u & 0x80000000u) ? ~u : (u | 0x80000000u);
}
__device__ inline float funkey(unsigned k) {
    unsigned u = (k & 0x80000000u) ? (k & 0x7fffffffu) : ~k;
    return __uint_as_float(u);
}

// ---- K1: single-block label planning: hist -> bucket layout -> worklist -> scatter ----
__global__ __launch_bounds__(1024) void plan_kernel(const int* __restrict__ lab,
                                                    WS* ws, int N) {
    __shared__ int h[8];       // class counts, 1..6
    __shared__ int S[8];       // bucket starts + end
    __shared__ int cur[8];     // scatter cursors
    const int tid = threadIdx.x;
    if (tid < 8) h[tid] = 0;
    __syncthreads();
    for (int i = tid; i < N; i += 1024) {
        int l = lab[i];
        if (l >= 1 && l <= 6) atomicAdd(&h[l], 1);
    }
    __syncthreads();
    if (tid == 0) {
        int acc = 0;
        for (int c = 1; c <= 6; ++c) { S[c] = acc; acc += ((h[c] + 31) >> 5) << 5; }
        S[7] = acc;
        int T = 0;
        for (int c = 1; c <= 6; ++c) {
            int nt = (h[c] + 31) >> 5;
            for (int k = 0; k < nt; ++k) { ws->wl_a[T] = S[c] + 32 * k; ws->wl_c[T] = c; ++T; }
        }
        ws->T = T;
        ws->done = 0u;
        for (int c = 0; c < 8; ++c) { ws->n[c] = h[c]; ws->S[c] = S[c]; }
        ws->S[7] = S[7];
    }
    __syncthreads();
    const int SEnd = S[7];
    for (int g = tid; g < SEnd; g += 1024) {      // sentinel init over padded range only
        ws->hpK[g] = 0xFFFFFFFFu;
        ws->hnK[g] = 0u;
        ws->labG[g] = -1;
    }
    if (tid < 8) cur[tid] = S[tid];
    __syncthreads();
    for (int i = tid; i < N; i += 1024) {          // scatter (order-invariant results)
        int l = lab[i];
        int g = -1;
        if (l >= 1 && l <= 6) { g = atomicAdd(&cur[l], 1); ws->labG[g] = l; }
        ws->gpos[i] = g;
    }
}

// ---- K2: L2-normalize bucketed rows -> bf16 at gathered position ----
__global__ __launch_bounds__(1024) void norm_gather_kernel(const float* __restrict__ in,
                                                           WS* ws) {
    int row  = blockIdx.x * 16 + (threadIdx.x >> 6);
    int lane = threadIdx.x & 63;
    int g = ws->gpos[row];                 // wave-uniform
    if (g < 0) return;                     // class not in a confused pair: never read
    float4 v = ((const float4*)(in + (size_t)row * Hdim))[lane];
    float ss = v.x*v.x + v.y*v.y + v.z*v.z + v.w*v.w;
    #pragma unroll
    for (int off = 32; off >= 1; off >>= 1) ss += __shfl_xor(ss, off);
    float sc = 1.0f / fmaxf(sqrtf(ss), 1e-12f);
    ushort4 o;
    o.x = f2bf(v.x * sc); o.y = f2bf(v.y * sc);
    o.z = f2bf(v.z * sc); o.w = f2bf(v.w * sc);
    ((ushort4*)(&ws->ebf[g][0]))[lane] = o;
}

// ---- K3: bucketed MFMA sim + positional min/max fold + fused last-block finalize ----
__global__ __launch_bounds__(256) void sim_kernel(WS* ws, float* __restrict__ out) {
    const int wave = threadIdx.x >> 6;
    const int lane = threadIdx.x & 63;
    const int col  = lane & 15;
    const int quad = lane >> 4;
    const int wid  = blockIdx.x * WPB + wave;
    const int tileIdx = wid / NSPLIT;
    const int split   = wid % NSPLIT;

    if (tileIdx < ws->T) {
        const int aBase = ws->wl_a[tileIdx];
        const int c     = ws->wl_c[tileIdx];
        const int p     = ((c - 1) ^ 1) + 1;        // confused partner: (1,2)(3,4)(5,6)
        const int posS = ws->S[c], posRealE = posS + ws->n[c];
        const int negS = ws->S[p], negRealE = negS + ws->n[p];
        const int nPosT = (ws->S[c + 1] - posS) >> 4;
        const int nT    = nPosT + ((((p == c + 1) ? ws->S[p + 1] : ws->S[p]) /*p<c => S[c]=end of p's pad*/
                                    - negS) >> 4);
        // NOTE: buckets are contiguous: padded end of bucket x is S[x+1]
        const int nNegT = ((ws->S[p + 1]) - negS) >> 4;
        const int nTT = nPosT + nNegT;

        const unsigned short* ebf = &ws->ebf[0][0];

        bf16x8 afrag[2][8];                          // resident A frags: [m=col][k=quad*8+j]
        #pragma unroll
        for (int t2 = 0; t2 < 2; ++t2) {
            const unsigned short* rp = ebf + (size_t)(aBase + t2 * 16 + col) * Hdim + quad * 8;
            #pragma unroll
            for (int ks = 0; ks < 8; ++ks)
                afrag[t2][ks] = *(const bf16x8*)(rp + ks * 32);
        }

        float runMin[2][4], runMax[2][4];
        #pragma unroll
        for (int t2 = 0; t2 < 2; ++t2)
            #pragma unroll
            for (int r = 0; r < 4; ++r) { runMin[t2][r] = BIGV; runMax[t2][r] = -BIGV; }

        auto j0Of = [&](int t) -> int {
            return (t < nPosT) ? (posS + (t << 4)) : (negS + ((t - nPosT) << 4));
        };
        bf16x8 b0[8], b1[8];
        auto loadB = [&](bf16x8 (&bf)[8], int t) {
            const unsigned short* rp = ebf + (size_t)(j0Of(t) + col) * Hdim + quad * 8;
            #pragma unroll
            for (int ks = 0; ks < 8; ++ks)
                bf[ks] = *(const bf16x8*)(rp + ks * 32);
        };
        auto computeT = [&](bf16x8 (&bf)[8], int t) {
            int j0 = j0Of(t);
            bool isPos = t < nPosT;                  // wave-uniform
            int realE  = isPos ? posRealE : negRealE;
            bool valid = (j0 + col) < realE;         // positional mask: one v_cmp per tile
            #pragma unroll
            for (int t2 = 0; t2 < 2; ++t2) {
                f32x4 acc = {0.f, 0.f, 0.f, 0.f};
                #pragma unroll
                for (int ks = 0; ks < 8; ++ks)
                    acc = __builtin_amdgcn_mfma_f32_16x16x32_bf16(afrag[t2][ks], bf[ks], acc, 0, 0, 0);
                if (isPos) {                         // self-inclusion OK: self-sim is max, min unaffected (n>=2 gated)
                    #pragma unroll
                    for (int r = 0; r < 4; ++r)
                        runMin[t2][r] = fminf(runMin[t2][r], valid ? acc[r] : BIGV);
                } else {
                    #pragma unroll
                    for (int r = 0; r < 4; ++r)
                        runMax[t2][r] = fmaxf(runMax[t2][r], valid ? acc[r] : -BIGV);
                }
            }
        };

        int nIter = (nTT > split) ? ((nTT - split + NSPLIT - 1) / NSPLIT) : 0;
        int t = split, i = 0;
        if (nIter > 0) loadB(b0, t);
        while (i + 2 <= nIter) {                     // register double-buffered pipeline
            loadB(b1, t + NSPLIT);
            computeT(b0, t);
            if (i + 2 < nIter) loadB(b0, t + 2 * NSPLIT);
            computeT(b1, t + NSPLIT);
            t += 2 * NSPLIT; i += 2;
        }
        if (i < nIter) computeT(b0, t);
        (void)nT;

        #pragma unroll
        for (int t2 = 0; t2 < 2; ++t2)
            #pragma unroll
            for (int r = 0; r < 4; ++r) {
                float mn = runMin[t2][r], mx = runMax[t2][r];
                #pragma unroll
                for (int off = 1; off < 16; off <<= 1) {
                    mn = fminf(mn, __shfl_xor(mn, off));
                    mx = fmaxf(mx, __shfl_xor(mx, off));
                }
                if (col == 0) {
                    int a = aBase + t2 * 16 + quad * 4 + r;
                    if (mn < 1e8f)  atomicMin(&ws->hpK[a], fkey(mn));   // commutative
                    if (mx > -1e8f) atomicMax(&ws->hnK[a], fkey(mx));
                }
            }
    }

    // ---- completion counter; last block finalizes ----
    __shared__ int isLast;
    __syncthreads();
    if (threadIdx.x == 0) {
        __threadfence();
        unsigned old = atomicAdd(&ws->done, 1u);
        isLast = (old == (unsigned)(gridDim.x - 1)) ? 1 : 0;
    }
    __syncthreads();
    if (!isLast) return;
    __threadfence();

    __shared__ int ncls[8];
    if (threadIdx.x < 8) ncls[threadIdx.x] = ws->n[threadIdx.x];
    __syncthreads();
    float sum = 0.f; int cnt = 0;
    const int SEnd = ws->S[7];
    for (int g = threadIdx.x; g < SEnd; g += 256) {
        int l = ws->labG[g];
        if (l >= 1) {                                // real slot, class 1..6
            int p = ((l - 1) ^ 1) + 1;
            if (ncls[l] >= 2 && ncls[p] >= 1) {      // has_pos && has_neg
                float hp = funkey(ws->hpK[g]);
                float hn = funkey(ws->hnK[g]);
                float tr = MARGIN + hn - hp;
                if (tr > 0.f) sum += tr;
                cnt += 1;
            }
        }
    }
    #pragma unroll
    for (int off = 32; off >= 1; off >>= 1) {
        sum += __shfl_xor(sum, off);
        cnt += __shfl_xor(cnt, off);
    }
    __shared__ float ssum[4]; __shared__ int scnt[4];
    int w = threadIdx.x >> 6;
    if ((threadIdx.x & 63) == 0) { ssum[w] = sum; scnt[w] = cnt; }
    __syncthreads();
    if (threadIdx.x == 0) {
        float ts = ssum[0] + ssum[1] + ssum[2] + ssum[3];
        int   tc = scnt[0] + scnt[1] + scnt[2] + scnt[3];
        out[0] = (tc > 0) ? ts / (float)tc : 0.f;
    }
}

extern "C" void kernel_launch(void* const* d_in, const int* in_sizes, int n_in,
                              void* d_out, int out_size, void* d_ws, size_t ws_size,
                              hipStream_t stream) {
    const float* emb = (const float*)d_in[0];
    const int*   lab = (const int*)d_in[1];
    int N = in_sizes[1];                               // 8192
    WS* ws = (WS*)d_ws;

    plan_kernel<<<1, 1024, 0, stream>>>(lab, ws, N);
    norm_gather_kernel<<<N / 16, 1024, 0, stream>>>(emb, ws);
    sim_kernel<<<SIMGRID, 256, 0, stream>>>(ws, (float*)d_out);
}

// Round 6
// 94.890 us; speedup vs baseline: 1.1732x; 1.1732x over previous
//
#include <hip/hip_runtime.h>
#include <math.h>

#define Hdim    256                    // embedding dim
#define NMAX    8192
#define NPADMAX (NMAX + 6 * 32)        // classes 1..6 bucketed, padded to 32
#define WLMAX   264                    // static sim grid: max 32-anchor tiles
#define BIGV    1e9f
#define MARGIN  0.5f

typedef __attribute__((ext_vector_type(8))) short bf16x8;   // MFMA A/B frag
typedef __attribute__((ext_vector_type(4))) float f32x4;    // MFMA C/D frag

struct WS {
    unsigned short ebf[NPADMAX][Hdim]; // bucket-sorted normalized bf16 rows (classes 1..6)
    int gpos[NMAX];                    // original row -> gathered row (-1 = not bucketed)
    int S[8];                          // S[1..6] bucket starts, S[7] = padded end
    int n[8];                          // real bucket counts
    int wl_a[WLMAX];                   // worklist: anchor base (gathered)
    int wl_c[WLMAX];                   // worklist: class
    int T;                             // worklist length
    unsigned done;                     // block completion counter
    float wsum;                        // triplet loss sum
    int   wcnt;                        // triplet count
};

__device__ inline unsigned short f2bf(float f) {    // fp32 -> bf16 RNE
    unsigned u = __float_as_uint(f);
    return (unsigned short)((u + 0x7fffu + ((u >> 16) & 1u)) >> 16);
}

// ---- K1: single-block planning: hist -> bucket layout -> worklist -> scatter ----
__global__ __launch_bounds__(1024) void plan_kernel(const int* __restrict__ lab,
                                                    WS* ws, int N) {
    __shared__ int h[8];       // class counts 1..6
    __shared__ int S[8];       // bucket starts + end
    __shared__ int cur[8];     // scatter cursors
    const int tid = threadIdx.x;
    if (tid < 8) h[tid] = 0;
    __syncthreads();
    for (int i = tid; i < N; i += 1024) {
        int l = lab[i];
        if (l >= 1 && l <= 6) atomicAdd(&h[l], 1);
    }
    __syncthreads();
    if (tid == 0) {
        int acc = 0;
        for (int c = 1; c <= 6; ++c) { S[c] = acc; acc += ((h[c] + 31) >> 5) << 5; }
        S[0] = 0; S[7] = acc;
        int T = 0;
        for (int c = 1; c <= 6; ++c) {
            int nt = (h[c] + 31) >> 5;
            for (int k = 0; k < nt; ++k) { ws->wl_a[T] = S[c] + 32 * k; ws->wl_c[T] = c; ++T; }
        }
        ws->T = T;
        ws->done = 0u; ws->wsum = 0.f; ws->wcnt = 0;
        for (int c = 0; c < 8; ++c) { ws->n[c] = h[c]; ws->S[c] = S[c]; }
    }
    __syncthreads();
    if (tid < 8) cur[tid] = S[tid];
    __syncthreads();
    for (int i = tid; i < N; i += 1024) {          // scatter (result order-invariant)
        int l = lab[i];
        ws->gpos[i] = (l >= 1 && l <= 6) ? atomicAdd(&cur[l], 1) : -1;
    }
}

// ---- K2: L2-normalize bucketed rows -> bf16 at gathered position ----
__global__ __launch_bounds__(256) void norm_gather_kernel(const float* __restrict__ in,
                                                          WS* ws) {
    int row  = blockIdx.x * 4 + (threadIdx.x >> 6);
    int lane = threadIdx.x & 63;
    int g = ws->gpos[row];                 // wave-uniform
    if (g < 0) return;                     // class not in any confused pair: never read
    float4 v = ((const float4*)(in + (size_t)row * Hdim))[lane];
    float ss = v.x*v.x + v.y*v.y + v.z*v.z + v.w*v.w;
    #pragma unroll
    for (int off = 32; off >= 1; off >>= 1) ss += __shfl_xor(ss, off);
    float sc = 1.0f / fmaxf(sqrtf(ss), 1e-12f);
    ushort4 o;
    o.x = f2bf(v.x * sc); o.y = f2bf(v.y * sc);
    o.z = f2bf(v.z * sc); o.w = f2bf(v.w * sc);
    ((ushort4*)(&ws->ebf[g][0]))[lane] = o;
}

// ---- K3: one block = one 32-anchor tile, full j-sweep; LDS combine; ~3 atomics/block ----
__global__ __launch_bounds__(256) void sim_kernel(WS* ws, float* __restrict__ out) {
    const int wave = threadIdx.x >> 6;
    const int lane = threadIdx.x & 63;
    const int col  = lane & 15;            // C col = j index
    const int quad = lane >> 4;            // C row group
    const int tileIdx = blockIdx.x;

    __shared__ float lds_hp[4][32], lds_hn[4][32];

    if (tileIdx < ws->T) {
        const int aBase = ws->wl_a[tileIdx];
        const int c     = ws->wl_c[tileIdx];
        const int p     = ((c - 1) ^ 1) + 1;          // confused partner: (1,2)(3,4)(5,6)
        const int posS = ws->S[c], posRealE = posS + ws->n[c];
        const int negS = ws->S[p], negRealE = negS + ws->n[p];
        const int nPosT = (ws->S[c + 1] - posS) >> 4; // padded bucket ends are S[x+1]
        const int nNegT = (ws->S[p + 1] - negS) >> 4;
        const int nTT   = nPosT + nNegT;
        const bool hasPN = (ws->n[c] >= 2) && (ws->n[p] >= 1);

        const unsigned short* ebf = &ws->ebf[0][0];

        bf16x8 afrag[2][8];                            // A frags: [m=col][k=quad*8+j]
        #pragma unroll
        for (int t2 = 0; t2 < 2; ++t2) {
            const unsigned short* rp = ebf + (size_t)(aBase + t2 * 16 + col) * Hdim + quad * 8;
            #pragma unroll
            for (int ks = 0; ks < 8; ++ks)
                afrag[t2][ks] = *(const bf16x8*)(rp + ks * 32);
        }

        float runMin[2][4], runMax[2][4];
        #pragma unroll
        for (int t2 = 0; t2 < 2; ++t2)
            #pragma unroll
            for (int r = 0; r < 4; ++r) { runMin[t2][r] = BIGV; runMax[t2][r] = -BIGV; }

        auto j0Of = [&](int t) -> int {
            return (t < nPosT) ? (posS + (t << 4)) : (negS + ((t - nPosT) << 4));
        };
        bf16x8 b0[8], b1[8];
        auto loadB = [&](bf16x8 (&bf)[8], int t) {
            const unsigned short* rp = ebf + (size_t)(j0Of(t) + col) * Hdim + quad * 8;
            #pragma unroll
            for (int ks = 0; ks < 8; ++ks)
                bf[ks] = *(const bf16x8*)(rp + ks * 32);
        };
        auto computeT = [&](bf16x8 (&bf)[8], int t) {
            int j0 = j0Of(t);
            bool isPos = t < nPosT;                    // wave-uniform
            int realE  = isPos ? posRealE : negRealE;
            bool valid = (j0 + col) < realE;           // positional mask, 1 v_cmp/tile
            #pragma unroll
            for (int t2 = 0; t2 < 2; ++t2) {
                f32x4 acc = {0.f, 0.f, 0.f, 0.f};
                #pragma unroll
                for (int ks = 0; ks < 8; ++ks)
                    acc = __builtin_amdgcn_mfma_f32_16x16x32_bf16(afrag[t2][ks], bf[ks], acc, 0, 0, 0);
                if (isPos) {                           // self-sim is max => min unaffected (n>=2 gated)
                    #pragma unroll
                    for (int r = 0; r < 4; ++r)
                        runMin[t2][r] = fminf(runMin[t2][r], valid ? acc[r] : BIGV);
                } else {
                    #pragma unroll
                    for (int r = 0; r < 4; ++r)
                        runMax[t2][r] = fmaxf(runMax[t2][r], valid ? acc[r] : -BIGV);
                }
            }
        };

        // 4 waves stride the j-tile list; register double-buffered
        int nIter = (nTT > wave) ? ((nTT - wave + 3) >> 2) : 0;
        int t = wave, i = 0;
        if (nIter > 0) loadB(b0, t);
        while (i + 2 <= nIter) {
            loadB(b1, t + 4);
            computeT(b0, t);
            if (i + 2 < nIter) loadB(b0, t + 8);
            computeT(b1, t + 4);
            t += 8; i += 2;
        }
        if (i < nIter) computeT(b0, t);

        // reduce across 16 cols; col==0 lanes stash per-wave results in LDS
        #pragma unroll
        for (int t2 = 0; t2 < 2; ++t2)
            #pragma unroll
            for (int r = 0; r < 4; ++r) {
                float mn = runMin[t2][r], mx = runMax[t2][r];
                #pragma unroll
                for (int off = 1; off < 16; off <<= 1) {
                    mn = fminf(mn, __shfl_xor(mn, off));
                    mx = fmaxf(mx, __shfl_xor(mx, off));
                }
                if (col == 0) {
                    int a = t2 * 16 + quad * 4 + r;
                    lds_hp[wave][a] = mn;
                    lds_hn[wave][a] = mx;
                }
            }
        __syncthreads();

        // wave 0: combine 4 waves, compute this tile's loss contribution
        if (wave == 0) {
            float contrib = 0.f; int cc = 0;
            if (lane < 32) {
                float hp = fminf(fminf(lds_hp[0][lane], lds_hp[1][lane]),
                                 fminf(lds_hp[2][lane], lds_hp[3][lane]));
                float hn = fmaxf(fmaxf(lds_hn[0][lane], lds_hn[1][lane]),
                                 fmaxf(lds_hn[2][lane], lds_hn[3][lane]));
                bool real = (aBase + lane) < posRealE;
                if (real && hasPN) {
                    float tr = MARGIN + hn - hp;
                    contrib = (tr > 0.f) ? tr : 0.f;
                    cc = 1;
                }
            }
            #pragma unroll
            for (int off = 32; off >= 1; off >>= 1) {
                contrib += __shfl_xor(contrib, off);
                cc      += __shfl_xor(cc, off);
            }
            if (lane == 0) {
                atomicAdd(&ws->wsum, contrib);
                atomicAdd(&ws->wcnt, cc);
            }
        }
    }

    // completion: same thread that issued data atomics drains them (s_waitcnt) first;
    // last block atomic-reads the totals. No threadfence / L2 writeback needed.
    if (threadIdx.x == 0) {
        __builtin_amdgcn_s_waitcnt(0);
        unsigned old = atomicAdd(&ws->done, 1u);
        if (old == (unsigned)(gridDim.x - 1)) {
            float s = atomicAdd(&ws->wsum, 0.0f);   // coherent atomic read
            int   n = atomicAdd(&ws->wcnt, 0);
            out[0] = (n > 0) ? s / (float)n : 0.f;
        }
    }
}

extern "C" void kernel_launch(void* const* d_in, const int* in_sizes, int n_in,
                              void* d_out, int out_size, void* d_ws, size_t ws_size,
                              hipStream_t stream) {
    const float* emb = (const float*)d_in[0];
    const int*   lab = (const int*)d_in[1];
    int N = in_sizes[1];                               // 8192
    WS* ws = (WS*)d_ws;

    plan_kernel<<<1, 1024, 0, stream>>>(lab, ws, N);
    norm_gather_kernel<<<(N + 3) / 4, 256, 0, stream>>>(emb, ws);
    sim_kernel<<<WLMAX, 256, 0, stream>>>(ws, (float*)d_out);
}